// Round 9
// baseline (3371.447 us; speedup 1.0000x reference)
//
#include <hip/hip_runtime.h>
#include <stdint.h>

// HydraAttention on MI355X (gfx950), R13.
// Model (fits R5/R6/R8/R10 counters quantitatively): GEMM util =
// MFMA / (MFMA + LDS-read + LDS-write) per CU, with read/MFMA overlap
// provided by INDEPENDENT BLOCKS per CU. R5 = worst ratio, best TLP (38%).
// My prior variants improved ratio but dropped to 1 block/CU. R13 gemm1:
// 256x256 tile, 4 waves x (128x128 out, 4x4 frags -> 15.6 B/kFLOP, half of
// R5), BK=32 single-buffered (LDS 32 KB -> ~4 blocks/CU, TLP preserved),
// R5's plain stage->sync->compute->sync schedule, R6's low-FETCH XCD map.
// Serial bound ~50%, predicted util 48-55%, gemm1 ~85-95us.
// gemm2 + small kernels byte-identical to R12 (single-variable change).
// Identity: out = invq[r] * (q @ (Wout*kv_b)^T) + b.

typedef short  short8   __attribute__((ext_vector_type(8)));
typedef float  floatx16 __attribute__((ext_vector_type(16)));

__device__ __forceinline__ void async16(const void* g, void* l) {
  __builtin_amdgcn_global_load_lds((const __attribute__((address_space(1))) void*)g,
                                   (__attribute__((address_space(3))) void*)l, 16, 0, 0);
}

__device__ __forceinline__ uint16_t f2bf(float f) {  // RNE fp32->bf16
  union { float f; uint32_t u; } x; x.f = f;
  uint32_t u = x.u;
  return (uint16_t)((u + 0x7fffu + ((u >> 16) & 1u)) >> 16);
}
__device__ __forceinline__ float bf2f(uint16_t h) {
  union { uint32_t u; float f; } x; x.u = ((uint32_t)h) << 16; return x.f;
}
__device__ __forceinline__ uint32_t pack2(float a, float b) {
  return (uint32_t)f2bf(a) | ((uint32_t)f2bf(b) << 16);
}
__device__ __forceinline__ void upk8(uint4 u, float* f) {
  f[0]=bf2f((uint16_t)u.x); f[1]=bf2f((uint16_t)(u.x>>16));
  f[2]=bf2f((uint16_t)u.y); f[3]=bf2f((uint16_t)(u.y>>16));
  f[4]=bf2f((uint16_t)u.z); f[5]=bf2f((uint16_t)(u.z>>16));
  f[6]=bf2f((uint16_t)u.w); f[7]=bf2f((uint16_t)(u.w>>16));
}

// ---------------- fused fp32->bf16 convert of 2 buffers ----------------
__global__ __launch_bounds__(256) void cvt2(
    const float* __restrict__ a, uint16_t* __restrict__ ao, int na,
    const float* __restrict__ b, uint16_t* __restrict__ bo, int nb) {
  int i = blockIdx.x * 256 + threadIdx.x;
  const float* in; uint16_t* out; int j = i;
  if (j < na) { in = a; out = ao; }
  else { j -= na; if (j >= nb) return; in = b; out = bo; }
  const float4* p = (const float4*)in;
  float4 u = p[(size_t)j * 2], v = p[(size_t)j * 2 + 1];
  uint4 o;
  o.x = pack2(u.x, u.y); o.y = pack2(u.z, u.w);
  o.z = pack2(v.x, v.y); o.w = pack2(v.z, v.w);
  ((uint4*)out)[j] = o;
}

// ---------------- GEMM1: qkv[16384,3072] = bf16( x @ Wqkv^T + bias ) ------
// 256x256 tile, BK=32, single-buffered 32 KiB LDS, 4 waves (2M x 2N),
// per-wave output 128x128 (acc 4x4 of 32x32). Plain R5 schedule.
__global__ __launch_bounds__(256, 4) void gemm1(
    const uint16_t* __restrict__ A, const uint16_t* __restrict__ Bw,
    const float* __restrict__ bias, uint16_t* __restrict__ Cb,
    int N, int K)
{
  __shared__ __align__(16) uint16_t As[256 * 32];   // 16 KiB
  __shared__ __align__(16) uint16_t Bs[256 * 32];   // 16 KiB
  const int tid = threadIdx.x;
  const int wave = tid >> 6, lane = tid & 63;
  const int l31 = lane & 31, khalf = lane >> 5;
  const int wm = wave & 1, wn = wave >> 1;          // 2x2 waves, 128x128 each
  const int id = blockIdx.x;
  const int xcd = id & 7, w = id >> 3;              // 768 blocks, 96/XCD
  const int tileM = ((w / 12) * 8 + xcd) * 256;     // 64 M-tiles (R6 map, low FETCH)
  const int tileN = (w % 12) * 256;                 // 12 N-tiles

  // staging: 4 threads/row (32 k = 4 x 16B granules), 64 rows/issue,
  // source granule pre-swizzled: LDS[r][p] = src[r][p ^ (r&3)]
  const int srow = tid >> 2;
  const int sk   = (tid & 3) ^ ((tid >> 2) & 3);
  const uint16_t* gA = A  + (size_t)(tileM + srow) * K + sk * 8;
  const uint16_t* gB = Bw + (size_t)(tileN + srow) * K + sk * 8;
  char* lA = (char*)As + tid * 16;
  char* lB = (char*)Bs + tid * 16;

  floatx16 acc[4][4];
#pragma unroll
  for (int mi = 0; mi < 4; mi++)
#pragma unroll
    for (int ni = 0; ni < 4; ni++)
#pragma unroll
      for (int r = 0; r < 16; r++) acc[mi][ni][r] = 0.f;

  const int arow0 = wm * 128 + l31;
  const int brow0 = wn * 128 + l31;

  for (int k0 = 0; k0 < K; k0 += 32) {
#pragma unroll
    for (int s = 0; s < 4; s++) {
      async16(gA + k0 + (size_t)s * 64 * K, lA + s * 4096);
      async16(gB + k0 + (size_t)s * 64 * K, lB + s * 4096);
    }
    __syncthreads();
#pragma unroll
    for (int ks = 0; ks < 2; ks++) {
      const int kc = khalf + ks * 2;                // granule 0..3
      short8 af[4], bfr[4];
#pragma unroll
      for (int mi = 0; mi < 4; mi++) {
        int r = arow0 + mi * 32;
        af[mi] = *(const short8*)&As[r * 32 + (kc ^ (r & 3)) * 8];
      }
#pragma unroll
      for (int ni = 0; ni < 4; ni++) {
        int r = brow0 + ni * 32;
        bfr[ni] = *(const short8*)&Bs[r * 32 + (kc ^ (r & 3)) * 8];
      }
#pragma unroll
      for (int mi = 0; mi < 4; mi++)
#pragma unroll
        for (int ni = 0; ni < 4; ni++)
          acc[mi][ni] = __builtin_amdgcn_mfma_f32_32x32x16_bf16(af[mi], bfr[ni], acc[mi][ni], 0, 0, 0);
    }
    __syncthreads();
  }

  // C/D layout 32x32: col = lane&31, row = (reg&3) + 8*(reg>>2) + 4*(lane>>5)
#pragma unroll
  for (int mi = 0; mi < 4; mi++) {
    const int rbase = tileM + wm * 128 + mi * 32 + 4 * khalf;
#pragma unroll
    for (int ni = 0; ni < 4; ni++) {
      const int col = tileN + wn * 128 + ni * 32 + l31;
      const float bv = bias[col];
#pragma unroll
      for (int reg = 0; reg < 16; reg++) {
        const int row = rbase + (reg & 3) + 8 * (reg >> 2);
        Cb[(size_t)row * N + col] = f2bf(acc[mi][ni][reg] + bv);
      }
    }
  }
}

// ---------------- GEMM2: out[16384,1024] = invq[r]*(q @ W'^T) + b ---------
// 128x256 tile, BK=64, 4 waves (2M x 2N), per-wave 64x128 out (R10/R12-exact).
__global__ __launch_bounds__(256, 2) void gemm2(
    const uint16_t* __restrict__ qkv, const float* __restrict__ invq,
    const uint16_t* __restrict__ Wp, const float* __restrict__ bias,
    float* __restrict__ Cf)
{
  __shared__ __align__(16) uint16_t As2[128 * 64];
  __shared__ __align__(16) uint16_t Bs2[256 * 64];
  const int tid = threadIdx.x;
  const int wave = tid >> 6, lane = tid & 63;
  const int l31 = lane & 31, khalf = lane >> 5;
  const int wm = wave & 1, wn = wave >> 1;
  // bijective XCD swizzle: 512 blocks = 8 XCDs x 64; N-panel = 128 wgids
  const int wgid = (blockIdx.x & 7) * 64 + (blockIdx.x >> 3);
  const int tileM = (wgid & 127) * 128;             // 128 M-tiles
  const int tileN = (wgid >> 7) * 256;              // 4 N-tiles
  const int batch = tileM >> 12;

  const int srow = wave * 8 + (lane >> 3);
  const int skc  = (lane & 7) ^ (lane >> 3);
  const uint16_t* gA = qkv + (size_t)(tileM + srow) * 3072 + skc * 8;  // q slice
  const uint16_t* gB = Wp + ((size_t)batch << 20) + (size_t)(tileN + srow) * 1024 + skc * 8;
  char* lA = (char*)As2 + wave * 1024;
  char* lB = (char*)Bs2 + wave * 1024;

  floatx16 acc[2][4];
#pragma unroll
  for (int mi = 0; mi < 2; mi++)
#pragma unroll
    for (int ni = 0; ni < 4; ni++)
#pragma unroll
      for (int r = 0; r < 16; r++) acc[mi][ni][r] = 0.f;

  const int arow0 = wm * 64 + l31;
  const int brow0 = wn * 128 + l31;

  for (int k0 = 0; k0 < 1024; k0 += 64) {
#pragma unroll
    for (int s = 0; s < 4; s++)
      async16(gA + k0 + (size_t)s * 32 * 3072, lA + s * 4096);
#pragma unroll
    for (int s = 0; s < 8; s++)
      async16(gB + k0 + (size_t)s * 32 * 1024, lB + s * 4096);
    __syncthreads();
#pragma unroll
    for (int ks = 0; ks < 4; ks++) {
      const int kc = khalf + ks * 2;
      short8 af[2], bfr[4];
#pragma unroll
      for (int mi = 0; mi < 2; mi++) {
        int r = arow0 + mi * 32;
        af[mi] = *(const short8*)&As2[(r * 8 + (kc ^ (r & 7))) * 8];
      }
#pragma unroll
      for (int ni = 0; ni < 4; ni++) {
        int r = brow0 + ni * 32;
        bfr[ni] = *(const short8*)&Bs2[(r * 8 + (kc ^ (r & 7))) * 8];
      }
#pragma unroll
      for (int mi = 0; mi < 2; mi++)
#pragma unroll
        for (int ni = 0; ni < 4; ni++)
          acc[mi][ni] = __builtin_amdgcn_mfma_f32_32x32x16_bf16(af[mi], bfr[ni], acc[mi][ni], 0, 0, 0);
    }
    __syncthreads();
  }

#pragma unroll
  for (int mi = 0; mi < 2; mi++) {
    const int rbase = tileM + wm * 64 + mi * 32 + 4 * khalf;
#pragma unroll
    for (int ni = 0; ni < 4; ni++) {
      const int col = tileN + wn * 128 + ni * 32 + l31;
      const float bv = bias[col];
#pragma unroll
      for (int reg = 0; reg < 16; reg++) {
        const int row = rbase + (reg & 3) + 8 * (reg >> 2);
        Cf[(size_t)row * 1024 + col] = fmaf(invq[row], acc[mi][ni][reg], bv);
      }
    }
  }
}

// -------- W'[b][n][k] = bf16( Wout[n][k] * kv[b][k] ), fp32 Wout ---------
__global__ __launch_bounds__(256) void scale_w(
    const float* __restrict__ wo, const float* __restrict__ kv,
    uint16_t* __restrict__ wp)
{
  int i = blockIdx.x * 256 + threadIdx.x;   // 4M elems / 8 = 512K threads
  int e = i << 3;
  int b = e >> 20;
  int k = e & 1023;
  float4 w0 = *(const float4*)(wo + (e & 0xFFFFF));
  float4 w1 = *(const float4*)(wo + (e & 0xFFFFF) + 4);
  float4 k0v = *(const float4*)(kv + (b << 10) + k);
  float4 k1v = *(const float4*)(kv + (b << 10) + k + 4);
  uint4 o;
  o.x = pack2(w0.x * k0v.x, w0.y * k0v.y);
  o.y = pack2(w0.z * k0v.z, w0.w * k0v.w);
  o.z = pack2(w1.x * k1v.x, w1.y * k1v.y);
  o.w = pack2(w1.z * k1v.z, w1.w * k1v.w);
  *(uint4*)(wp + e) = o;
}

// ---------------- mask layout detection (harness-verified) ----------------
__global__ __launch_bounds__(256) void detect_mask(const unsigned char* __restrict__ m,
                                                   int* __restrict__ flag) {
  int i = blockIdx.x * blockDim.x + threadIdx.x;
  int v = ((i & 3) != 0) ? (int)m[i] : 0;
  unsigned long long b = __ballot(v != 0);
  if ((threadIdx.x & 63) == 0 && b) atomicOr(flag, 1);
}

// ---------------- per-row norms + kv reduction (512 blocks) ----------------
__global__ __launch_bounds__(256) void rownorm_kv(
    const uint16_t* __restrict__ qkv, const void* __restrict__ maskbuf,
    const int* __restrict__ flag, float* __restrict__ invq, float* __restrict__ kv)
{
  __shared__ float kvloc[1024];
  const int tid = threadIdx.x;
  for (int i = tid; i < 1024; i += 256) kvloc[i] = 0.f;
  __syncthreads();
  const int wave = tid >> 6, lane = tid & 63;
  const int b = blockIdx.x >> 7;
  const int chunk = blockIdx.x & 127;
  const int isU8 = *flag;
  const unsigned char* m8 = (const unsigned char*)maskbuf;
  const int* m32 = (const int*)maskbuf;

  float kvacc[16];
#pragma unroll
  for (int i = 0; i < 16; i++) kvacc[i] = 0.f;

  const int r0 = b * 4096 + chunk * 32 + wave * 8;
#pragma unroll 2
  for (int j = 0; j < 8; j++) {
    int r = r0 + j;
    const uint16_t* rp = qkv + (size_t)r * 3072;
    uint4 q0 = *(const uint4*)(rp + lane * 16);
    uint4 q1 = *(const uint4*)(rp + lane * 16 + 8);
    uint4 k0 = *(const uint4*)(rp + 1024 + lane * 16);
    uint4 k1 = *(const uint4*)(rp + 1024 + lane * 16 + 8);
    uint4 v0 = *(const uint4*)(rp + 2048 + lane * 16);
    uint4 v1 = *(const uint4*)(rp + 2048 + lane * 16 + 8);
    float qf[16], kf[16], vf[16];
    upk8(q0, qf); upk8(q1, qf + 8);
    upk8(k0, kf); upk8(k1, kf + 8);
    upk8(v0, vf); upk8(v1, vf + 8);
    float sq = 0.f, sk = 0.f;
#pragma unroll
    for (int i = 0; i < 16; i++) { sq = fmaf(qf[i], qf[i], sq); sk = fmaf(kf[i], kf[i], sk); }
    for (int off = 32; off; off >>= 1) { sq += __shfl_xor(sq, off); sk += __shfl_xor(sk, off); }
    float rq = rsqrtf(sq), rk = rsqrtf(sk);
    if (lane == 0) invq[r] = rq;
    int masked = isU8 ? (int)m8[r] : m32[r];
    if (!masked) {
#pragma unroll
      for (int i = 0; i < 16; i++) kvacc[i] = fmaf(kf[i] * rk, vf[i], kvacc[i]);
    }
  }
#pragma unroll
  for (int i = 0; i < 16; i++) atomicAdd(&kvloc[lane * 16 + i], kvacc[i]);
  __syncthreads();
  for (int i = tid; i < 1024; i += 256) atomicAdd(&kv[b * 1024 + i], kvloc[i]);
}

extern "C" void kernel_launch(void* const* d_in, const int* in_sizes, int n_in,
                              void* d_out, int out_size, void* d_ws, size_t ws_size,
                              hipStream_t stream) {
  const float* x     = (const float*)d_in[0];
  const void*  mask  = d_in[1];
  const float* W_qkv = (const float*)d_in[2];
  const float* b_qkv = (const float*)d_in[3];
  const float* W_out = (const float*)d_in[4];
  const float* b_out = (const float*)d_in[5];
  float* out = (float*)d_out;

  const int BT = 4 * 4096;  // 16384 rows
  const int D  = 1024;

  char* ws = (char*)d_ws;
  size_t off = 0;
  auto alloc = [&](size_t bytes) { size_t r = off; off += (bytes + 255) & ~(size_t)255; return r; };
  size_t o_xb   = alloc((size_t)BT * D * 2);        // x bf16
  size_t o_qkvb = alloc((size_t)BT * 3 * D * 2);    // qkv bf16
  size_t o_wq   = alloc((size_t)3 * D * D * 2);     // W_qkv bf16
  size_t o_wp   = alloc((size_t)4 * D * D * 2);     // W' = Wout*kv_b, per batch
  size_t o_kv   = alloc((size_t)4 * D * 4 + 256);   // kv (fp32) + flag
  size_t o_invq = alloc((size_t)BT * 4);            // 1/||q|| per row

  uint16_t* xb   = (uint16_t*)(ws + o_xb);
  uint16_t* qkvb = (uint16_t*)(ws + o_qkvb);
  uint16_t* wq   = (uint16_t*)(ws + o_wq);
  uint16_t* wp   = (uint16_t*)(ws + o_wp);
  float*    kv   = (float*)(ws + o_kv);
  int*      flag = (int*)(ws + o_kv + (size_t)4 * D * 4);
  float*    invq = (float*)(ws + o_invq);

  hipMemsetAsync(ws + o_kv, 0, (size_t)4 * D * 4 + 256, stream);
  {
    int na = BT * D / 8, nb = 3 * D * D / 8;
    int tot = na + nb;
    cvt2<<<dim3((tot + 255) / 256), 256, 0, stream>>>(x, xb, na, W_qkv, wq, nb);
  }
  detect_mask<<<dim3(64), 256, 0, stream>>>((const unsigned char*)mask, flag);
  gemm1<<<dim3(768), 256, 0, stream>>>(xb, wq, b_qkv, qkvb, 3 * D, D);
  rownorm_kv<<<dim3(512), 256, 0, stream>>>(qkvb, mask, flag, invq, kv);
  scale_w<<<dim3(4 * D * D / 8 / 256), 256, 0, stream>>>(W_out, kv, wp);
  gemm2<<<dim3(512), 256, 0, stream>>>(qkvb, invq, wp, b_out, out);
}

// Round 10
// 331.138 us; speedup vs baseline: 10.1814x; 10.1814x over previous
//
#include <hip/hip_runtime.h>
#include <stdint.h>

// HydraAttention on MI355X (gfx950), R14.
// R13 post-mortem: (1) lane-divergent LDS dest for global_load_lds ->
// compiler waterfall, 56x FETCH; (2) launch_bounds(256,4) + 256-reg acc ->
// scratch spill. Both fixed by construction here.
// gemm1 rebuilt on the key insight: with mfma 16x16x32 + BK=32, one
// ds_read_b128 frag load covers 16 rows x full 64B row = 1024 contiguous
// bytes, every byte once -> ZERO bank conflicts, no swizzle needed
// (32x32x16 reads 32 rows x one 16B granule -> conflicts intrinsic).
// Structure: 256x256 tile, 512 thr / 8 waves (2Mx4N), per-wave 128x64 out
// (acc[8][4] x f32x4 = 128 regs), 3-slot LDS ring (96 KB) staging tile t+2
// while computing t (slot (t+2)%3 != t%3: no overwrite hazard), counted
// vmcnt(8) gate (never 0 until epilogue), raw s_barrier + lgkmcnt(0).
// gemm2 + small kernels byte-exact R12 (single-variable change).
// Identity: out = invq[r] * (q @ (Wout*kv_b)^T) + b.

typedef short  short8   __attribute__((ext_vector_type(8)));
typedef float  floatx16 __attribute__((ext_vector_type(16)));
typedef float  floatx4  __attribute__((ext_vector_type(4)));

__device__ __forceinline__ void async16(const void* g, void* l) {
  __builtin_amdgcn_global_load_lds((const __attribute__((address_space(1))) void*)g,
                                   (__attribute__((address_space(3))) void*)l, 16, 0, 0);
}

__device__ __forceinline__ uint16_t f2bf(float f) {  // RNE fp32->bf16
  union { float f; uint32_t u; } x; x.f = f;
  uint32_t u = x.u;
  return (uint16_t)((u + 0x7fffu + ((u >> 16) & 1u)) >> 16);
}
__device__ __forceinline__ float bf2f(uint16_t h) {
  union { uint32_t u; float f; } x; x.u = ((uint32_t)h) << 16; return x.f;
}
__device__ __forceinline__ uint32_t pack2(float a, float b) {
  return (uint32_t)f2bf(a) | ((uint32_t)f2bf(b) << 16);
}
__device__ __forceinline__ void upk8(uint4 u, float* f) {
  f[0]=bf2f((uint16_t)u.x); f[1]=bf2f((uint16_t)(u.x>>16));
  f[2]=bf2f((uint16_t)u.y); f[3]=bf2f((uint16_t)(u.y>>16));
  f[4]=bf2f((uint16_t)u.z); f[5]=bf2f((uint16_t)(u.z>>16));
  f[6]=bf2f((uint16_t)u.w); f[7]=bf2f((uint16_t)(u.w>>16));
}

// ---------------- fused fp32->bf16 convert of 2 buffers ----------------
__global__ __launch_bounds__(256) void cvt2(
    const float* __restrict__ a, uint16_t* __restrict__ ao, int na,
    const float* __restrict__ b, uint16_t* __restrict__ bo, int nb) {
  int i = blockIdx.x * 256 + threadIdx.x;
  const float* in; uint16_t* out; int j = i;
  if (j < na) { in = a; out = ao; }
  else { j -= na; if (j >= nb) return; in = b; out = bo; }
  const float4* p = (const float4*)in;
  float4 u = p[(size_t)j * 2], v = p[(size_t)j * 2 + 1];
  uint4 o;
  o.x = pack2(u.x, u.y); o.y = pack2(u.z, u.w);
  o.z = pack2(v.x, v.y); o.w = pack2(v.z, v.w);
  ((uint4*)out)[j] = o;
}

// ---------------- GEMM1: qkv[16384,3072] = bf16( x @ Wqkv^T + bias ) ------
// 256x256 tile, BK=32, 3-slot ring, 8 waves, mfma 16x16x32.
#define G1NT 32   // K=1024 / 32

__global__ __launch_bounds__(512, 2) void gemm1(
    const uint16_t* __restrict__ A, const uint16_t* __restrict__ Bw,
    const float* __restrict__ bias, uint16_t* __restrict__ Cb)
{
  __shared__ __align__(16) uint16_t As[3][8192];   // 3 x 256r x 32k = 48 KiB
  __shared__ __align__(16) uint16_t Bs[3][8192];   // 48 KiB
  const int tid = threadIdx.x;
  const int wave = tid >> 6, lane = tid & 63;
  const int l15 = lane & 15, kq = lane >> 4;       // row-in-frag, k-quarter
  const int wm = wave >> 2, wn = wave & 3;         // 2M x 4N waves
  const int id = blockIdx.x;
  const int xcd = id & 7, w = id >> 3;             // 768 blocks, 96/XCD
  const int tileM = ((w / 12) * 8 + xcd) * 256;    // 64 M-tiles (R6 map)
  const int tileN = (w % 12) * 256;                // 12 N-tiles

  // staging: linear copy. thread t -> row (t>>2)+issue*128, granule t&3.
  // LDS dest is WAVE-UNIFORM base + lane*16 (hardware requirement).
  const int srow = tid >> 2;
  const uint16_t* gA = A  + (size_t)(tileM + srow) * 1024 + (tid & 3) * 8;
  const uint16_t* gB = Bw + (size_t)(tileN + srow) * 1024 + (tid & 3) * 8;

  floatx4 acc[8][4];
#pragma unroll
  for (int mi = 0; mi < 8; mi++)
#pragma unroll
    for (int ni = 0; ni < 4; ni++)
#pragma unroll
      for (int r = 0; r < 4; r++) acc[mi][ni][r] = 0.f;

#define STG1(tt) { const int sl_ = (tt) % 3; const size_t ko_ = (size_t)(tt) * 32; \
    async16(gA + ko_,                      (char*)As[sl_] + wave * 1024); \
    async16(gA + ko_ + (size_t)128 * 1024, (char*)As[sl_] + 8192 + wave * 1024); \
    async16(gB + ko_,                      (char*)Bs[sl_] + wave * 1024); \
    async16(gB + ko_ + (size_t)128 * 1024, (char*)Bs[sl_] + 8192 + wave * 1024); }

  STG1(0); STG1(1);

#pragma unroll 1
  for (int t = 0; t < G1NT; ++t) {
    if (t + 2 < G1NT) STG1(t + 2);
    // gate: tile t's 4 loads landed (8 = tiles t+1,t+2 still in flight)
    if (t + 2 < G1NT)      asm volatile("s_waitcnt vmcnt(8)" ::: "memory");
    else if (t + 1 < G1NT) asm volatile("s_waitcnt vmcnt(4)" ::: "memory");
    else                   asm volatile("s_waitcnt vmcnt(0)" ::: "memory");
    __builtin_amdgcn_s_barrier();            // all waves gated -> tile t in LDS
    asm volatile("" ::: "memory");

    const uint16_t* Ac = As[t % 3];
    const uint16_t* Bc = Bs[t % 3];
    short8 aF[8], bF[4];
#pragma unroll
    for (int mi = 0; mi < 8; mi++)           // 16 rows x 64B: conflict-free
      aF[mi] = *(const short8*)&Ac[(wm * 128 + mi * 16 + l15) * 32 + kq * 8];
#pragma unroll
    for (int ni = 0; ni < 4; ni++)
      bF[ni] = *(const short8*)&Bc[(wn * 64 + ni * 16 + l15) * 32 + kq * 8];
#pragma unroll
    for (int mi = 0; mi < 8; mi++)
#pragma unroll
      for (int ni = 0; ni < 4; ni++)
        acc[mi][ni] = __builtin_amdgcn_mfma_f32_16x16x32_bf16(aF[mi], bF[ni], acc[mi][ni], 0, 0, 0);

    asm volatile("s_waitcnt lgkmcnt(0)" ::: "memory");  // reads done before slot reuse
    __builtin_amdgcn_s_barrier();
    asm volatile("" ::: "memory");
  }
#undef STG1

  // C/D 16x16: col = lane&15, row = (lane>>4)*4 + reg  (m89-verified)
#pragma unroll
  for (int mi = 0; mi < 8; mi++) {
    const int rbase = tileM + wm * 128 + mi * 16 + kq * 4;
#pragma unroll
    for (int ni = 0; ni < 4; ni++) {
      const int col = tileN + wn * 64 + ni * 16 + l15;
      const float bv = bias[col];
#pragma unroll
      for (int reg = 0; reg < 4; reg++)
        Cb[(size_t)(rbase + reg) * 3072 + col] = f2bf(acc[mi][ni][reg] + bv);
    }
  }
}

// ---------------- GEMM2: out[16384,1024] = invq[r]*(q @ W'^T) + b ---------
// 128x256 tile, BK=64, 4 waves (2M x 2N), per-wave 64x128 out (R12-exact).
__global__ __launch_bounds__(256, 2) void gemm2(
    const uint16_t* __restrict__ qkv, const float* __restrict__ invq,
    const uint16_t* __restrict__ Wp, const float* __restrict__ bias,
    float* __restrict__ Cf)
{
  __shared__ __align__(16) uint16_t As2[128 * 64];
  __shared__ __align__(16) uint16_t Bs2[256 * 64];
  const int tid = threadIdx.x;
  const int wave = tid >> 6, lane = tid & 63;
  const int l31 = lane & 31, khalf = lane >> 5;
  const int wm = wave & 1, wn = wave >> 1;
  // bijective XCD swizzle: 512 blocks = 8 XCDs x 64; N-panel = 128 wgids
  const int wgid = (blockIdx.x & 7) * 64 + (blockIdx.x >> 3);
  const int tileM = (wgid & 127) * 128;             // 128 M-tiles
  const int tileN = (wgid >> 7) * 256;              // 4 N-tiles
  const int batch = tileM >> 12;

  const int srow = wave * 8 + (lane >> 3);
  const int skc  = (lane & 7) ^ (lane >> 3);
  const uint16_t* gA = qkv + (size_t)(tileM + srow) * 3072 + skc * 8;  // q slice
  const uint16_t* gB = Wp + ((size_t)batch << 20) + (size_t)(tileN + srow) * 1024 + skc * 8;
  char* lA = (char*)As2 + wave * 1024;
  char* lB = (char*)Bs2 + wave * 1024;

  floatx16 acc[2][4];
#pragma unroll
  for (int mi = 0; mi < 2; mi++)
#pragma unroll
    for (int ni = 0; ni < 4; ni++)
#pragma unroll
      for (int r = 0; r < 16; r++) acc[mi][ni][r] = 0.f;

  const int arow0 = wm * 64 + l31;
  const int brow0 = wn * 128 + l31;

  for (int k0 = 0; k0 < 1024; k0 += 64) {
#pragma unroll
    for (int s = 0; s < 4; s++)
      async16(gA + k0 + (size_t)s * 32 * 3072, lA + s * 4096);
#pragma unroll
    for (int s = 0; s < 8; s++)
      async16(gB + k0 + (size_t)s * 32 * 1024, lB + s * 4096);
    __syncthreads();
#pragma unroll
    for (int ks = 0; ks < 4; ks++) {
      const int kc = khalf + ks * 2;
      short8 af[2], bfr[4];
#pragma unroll
      for (int mi = 0; mi < 2; mi++) {
        int r = arow0 + mi * 32;
        af[mi] = *(const short8*)&As2[(r * 8 + (kc ^ (r & 7))) * 8];
      }
#pragma unroll
      for (int ni = 0; ni < 4; ni++) {
        int r = brow0 + ni * 32;
        bfr[ni] = *(const short8*)&Bs2[(r * 8 + (kc ^ (r & 7))) * 8];
      }
#pragma unroll
      for (int mi = 0; mi < 2; mi++)
#pragma unroll
        for (int ni = 0; ni < 4; ni++)
          acc[mi][ni] = __builtin_amdgcn_mfma_f32_32x32x16_bf16(af[mi], bfr[ni], acc[mi][ni], 0, 0, 0);
    }
    __syncthreads();
  }

#pragma unroll
  for (int mi = 0; mi < 2; mi++) {
    const int rbase = tileM + wm * 64 + mi * 32 + 4 * khalf;
#pragma unroll
    for (int ni = 0; ni < 4; ni++) {
      const int col = tileN + wn * 128 + ni * 32 + l31;
      const float bv = bias[col];
#pragma unroll
      for (int reg = 0; reg < 16; reg++) {
        const int row = rbase + (reg & 3) + 8 * (reg >> 2);
        Cf[(size_t)row * 1024 + col] = fmaf(invq[row], acc[mi][ni][reg], bv);
      }
    }
  }
}

// -------- W'[b][n][k] = bf16( Wout[n][k] * kv[b][k] ), fp32 Wout ---------
__global__ __launch_bounds__(256) void scale_w(
    const float* __restrict__ wo, const float* __restrict__ kv,
    uint16_t* __restrict__ wp)
{
  int i = blockIdx.x * 256 + threadIdx.x;   // 4M elems / 8 = 512K threads
  int e = i << 3;
  int b = e >> 20;
  int k = e & 1023;
  float4 w0 = *(const float4*)(wo + (e & 0xFFFFF));
  float4 w1 = *(const float4*)(wo + (e & 0xFFFFF) + 4);
  float4 k0v = *(const float4*)(kv + (b << 10) + k);
  float4 k1v = *(const float4*)(kv + (b << 10) + k + 4);
  uint4 o;
  o.x = pack2(w0.x * k0v.x, w0.y * k0v.y);
  o.y = pack2(w0.z * k0v.z, w0.w * k0v.w);
  o.z = pack2(w1.x * k1v.x, w1.y * k1v.y);
  o.w = pack2(w1.z * k1v.z, w1.w * k1v.w);
  *(uint4*)(wp + e) = o;
}

// ---------------- mask layout detection (harness-verified) ----------------
__global__ __launch_bounds__(256) void detect_mask(const unsigned char* __restrict__ m,
                                                   int* __restrict__ flag) {
  int i = blockIdx.x * blockDim.x + threadIdx.x;
  int v = ((i & 3) != 0) ? (int)m[i] : 0;
  unsigned long long b = __ballot(v != 0);
  if ((threadIdx.x & 63) == 0 && b) atomicOr(flag, 1);
}

// ---------------- per-row norms + kv reduction (512 blocks) ----------------
__global__ __launch_bounds__(256) void rownorm_kv(
    const uint16_t* __restrict__ qkv, const void* __restrict__ maskbuf,
    const int* __restrict__ flag, float* __restrict__ invq, float* __restrict__ kv)
{
  __shared__ float kvloc[1024];
  const int tid = threadIdx.x;
  for (int i = tid; i < 1024; i += 256) kvloc[i] = 0.f;
  __syncthreads();
  const int wave = tid >> 6, lane = tid & 63;
  const int b = blockIdx.x >> 7;
  const int chunk = blockIdx.x & 127;
  const int isU8 = *flag;
  const unsigned char* m8 = (const unsigned char*)maskbuf;
  const int* m32 = (const int*)maskbuf;

  float kvacc[16];
#pragma unroll
  for (int i = 0; i < 16; i++) kvacc[i] = 0.f;

  const int r0 = b * 4096 + chunk * 32 + wave * 8;
#pragma unroll 2
  for (int j = 0; j < 8; j++) {
    int r = r0 + j;
    const uint16_t* rp = qkv + (size_t)r * 3072;
    uint4 q0 = *(const uint4*)(rp + lane * 16);
    uint4 q1 = *(const uint4*)(rp + lane * 16 + 8);
    uint4 k0 = *(const uint4*)(rp + 1024 + lane * 16);
    uint4 k1 = *(const uint4*)(rp + 1024 + lane * 16 + 8);
    uint4 v0 = *(const uint4*)(rp + 2048 + lane * 16);
    uint4 v1 = *(const uint4*)(rp + 2048 + lane * 16 + 8);
    float qf[16], kf[16], vf[16];
    upk8(q0, qf); upk8(q1, qf + 8);
    upk8(k0, kf); upk8(k1, kf + 8);
    upk8(v0, vf); upk8(v1, vf + 8);
    float sq = 0.f, sk = 0.f;
#pragma unroll
    for (int i = 0; i < 16; i++) { sq = fmaf(qf[i], qf[i], sq); sk = fmaf(kf[i], kf[i], sk); }
    for (int off = 32; off; off >>= 1) { sq += __shfl_xor(sq, off); sk += __shfl_xor(sk, off); }
    float rq = rsqrtf(sq), rk = rsqrtf(sk);
    if (lane == 0) invq[r] = rq;
    int masked = isU8 ? (int)m8[r] : m32[r];
    if (!masked) {
#pragma unroll
      for (int i = 0; i < 16; i++) kvacc[i] = fmaf(kf[i] * rk, vf[i], kvacc[i]);
    }
  }
#pragma unroll
  for (int i = 0; i < 16; i++) atomicAdd(&kvloc[lane * 16 + i], kvacc[i]);
  __syncthreads();
  for (int i = tid; i < 1024; i += 256) atomicAdd(&kv[b * 1024 + i], kvloc[i]);
}

extern "C" void kernel_launch(void* const* d_in, const int* in_sizes, int n_in,
                              void* d_out, int out_size, void* d_ws, size_t ws_size,
                              hipStream_t stream) {
  const float* x     = (const float*)d_in[0];
  const void*  mask  = d_in[1];
  const float* W_qkv = (const float*)d_in[2];
  const float* b_qkv = (const float*)d_in[3];
  const float* W_out = (const float*)d_in[4];
  const float* b_out = (const float*)d_in[5];
  float* out = (float*)d_out;

  const int BT = 4 * 4096;  // 16384 rows
  const int D  = 1024;

  char* ws = (char*)d_ws;
  size_t off = 0;
  auto alloc = [&](size_t bytes) { size_t r = off; off += (bytes + 255) & ~(size_t)255; return r; };
  size_t o_xb   = alloc((size_t)BT * D * 2);        // x bf16
  size_t o_qkvb = alloc((size_t)BT * 3 * D * 2);    // qkv bf16
  size_t o_wq   = alloc((size_t)3 * D * D * 2);     // W_qkv bf16
  size_t o_wp   = alloc((size_t)4 * D * D * 2);     // W' = Wout*kv_b, per batch
  size_t o_kv   = alloc((size_t)4 * D * 4 + 256);   // kv (fp32) + flag
  size_t o_invq = alloc((size_t)BT * 4);            // 1/||q|| per row

  uint16_t* xb   = (uint16_t*)(ws + o_xb);
  uint16_t* qkvb = (uint16_t*)(ws + o_qkvb);
  uint16_t* wq   = (uint16_t*)(ws + o_wq);
  uint16_t* wp   = (uint16_t*)(ws + o_wp);
  float*    kv   = (float*)(ws + o_kv);
  int*      flag = (int*)(ws + o_kv + (size_t)4 * D * 4);
  float*    invq = (float*)(ws + o_invq);

  hipMemsetAsync(ws + o_kv, 0, (size_t)4 * D * 4 + 256, stream);
  {
    int na = BT * D / 8, nb = 3 * D * D / 8;
    int tot = na + nb;
    cvt2<<<dim3((tot + 255) / 256), 256, 0, stream>>>(x, xb, na, W_qkv, wq, nb);
  }
  detect_mask<<<dim3(64), 256, 0, stream>>>((const unsigned char*)mask, flag);
  gemm1<<<dim3(768), 512, 0, stream>>>(xb, wq, b_qkv, qkvb);
  rownorm_kv<<<dim3(512), 256, 0, stream>>>(qkvb, mask, flag, invq, kv);
  scale_w<<<dim3(4 * D * D / 8 / 256), 256, 0, stream>>>(W_out, kv, wp);
  gemm2<<<dim3(512), 256, 0, stream>>>(qkvb, invq, wp, b_out, out);
}